// Round 1
// baseline (298.752 us; speedup 1.0000x reference)
//
#include <hip/hip_runtime.h>
#include <hip/hip_bf16.h>

typedef float ff4 __attribute__((ext_vector_type(4)));
typedef short s8v __attribute__((ext_vector_type(8)));
typedef unsigned int u4v __attribute__((ext_vector_type(4)));
typedef unsigned int u2v __attribute__((ext_vector_type(2)));

#define Hd 1024
#define Nn 256
#define RB 64
#define KC 64
#define SPAD 72    // bf16 stride for s/d/mem LDS tiles (64 + 8 pad)
#define APAD 264   // bf16 stride for attn LDS tile (256 + 8 pad)

__device__ __forceinline__ unsigned bf16r(float f) {
    unsigned u = __builtin_bit_cast(unsigned, f);
    return (u + 0x7FFFu + ((u >> 16) & 1u)) >> 16;   // RNE f32->bf16
}

// ---- convert memory f32 [256][1024] -> bf16 (same layout) ----
__global__ void conv_mem_kernel(const float* __restrict__ mem, unsigned short* __restrict__ memB) {
    int i = (blockIdx.x * 256 + threadIdx.x) * 4;
    ff4 v = *(const ff4*)(mem + i);
    u2v p;
    p[0] = bf16r(v[0]) | (bf16r(v[1]) << 16);
    p[1] = bf16r(v[2]) | (bf16r(v[3]) << 16);
    *(u2v*)(memB + i) = p;
}

// ---- Gram matrix G = mem @ mem^T  [256][256], written as bf16 ----
__global__ __launch_bounds__(256) void gram_kernel(const float* __restrict__ mem,
                                                   unsigned short* __restrict__ Gbf) {
    __shared__ float LA[32][132];
    __shared__ float LB[32][132];
    const int t = threadIdx.x;
    const int bi = blockIdx.x >> 3, bj = blockIdx.x & 7;
    const int j = t & 31, i0 = t >> 5;   // j: col in tile, i0: 0..7
    float acc0 = 0.f, acc1 = 0.f, acc2 = 0.f, acc3 = 0.f;
    for (int kc = 0; kc < Hd; kc += 128) {
        __syncthreads();
#pragma unroll
        for (int q = 0; q < 4; ++q) {
            int c = t + q * 256;           // 0..1023 float4 slots
            int r = c >> 5, fc = (c & 31) << 2;
            *(ff4*)&LA[r][fc] = *(const ff4*)(mem + (size_t)(bi * 32 + r) * Hd + kc + fc);
            *(ff4*)&LB[r][fc] = *(const ff4*)(mem + (size_t)(bj * 32 + r) * Hd + kc + fc);
        }
        __syncthreads();
#pragma unroll 4
        for (int kk = 0; kk < 128; kk += 4) {
            ff4 b = *(const ff4*)&LB[j][kk];
            ff4 a0 = *(const ff4*)&LA[i0][kk];
            ff4 a1 = *(const ff4*)&LA[i0 + 8][kk];
            ff4 a2 = *(const ff4*)&LA[i0 + 16][kk];
            ff4 a3 = *(const ff4*)&LA[i0 + 24][kk];
            acc0 += a0[0]*b[0] + a0[1]*b[1] + a0[2]*b[2] + a0[3]*b[3];
            acc1 += a1[0]*b[0] + a1[1]*b[1] + a1[2]*b[2] + a1[3]*b[3];
            acc2 += a2[0]*b[0] + a2[1]*b[1] + a2[2]*b[2] + a2[3]*b[3];
            acc3 += a3[0]*b[0] + a3[1]*b[1] + a3[2]*b[2] + a3[3]*b[3];
        }
    }
    const int gj = bj * 32 + j;
    Gbf[(size_t)(bi * 32 + i0 +  0) * Nn + gj] = (unsigned short)bf16r(acc0);
    Gbf[(size_t)(bi * 32 + i0 +  8) * Nn + gj] = (unsigned short)bf16r(acc1);
    Gbf[(size_t)(bi * 32 + i0 + 16) * Nn + gj] = (unsigned short)bf16r(acc2);
    Gbf[(size_t)(bi * 32 + i0 + 24) * Nn + gj] = (unsigned short)bf16r(acc3);
}

// ---- fused main kernel: 64 rows/block, 4 waves x 16 rows ----
__global__ __launch_bounds__(256, 2) void fused_kernel(
    const float* __restrict__ user, const float* __restrict__ music,
    const float* __restrict__ Wout, const float* __restrict__ bout,
    const int* __restrict__ label, const unsigned short* __restrict__ memB,
    const unsigned short* __restrict__ Gbf,
    float* __restrict__ out, float* __restrict__ partials)
{
    __shared__ __align__(16) unsigned char smem[55808];
    unsigned short* sS = (unsigned short*)smem;          // [64][72] bf16 s
    unsigned short* sD = sS + RB * SPAD;                 // [64][72] bf16 d
    unsigned short* sM = sD + RB * SPAD;                 // [256][72] bf16 mem chunk (aliased by attn later)
    float* sAux   = (float*)(smem + 55296);              // [64] sum d^2 per row
    float* sScore = (float*)(smem + 55552);              // [64] mask*score per row

    const int t = threadIdx.x;
    const int w = t >> 6;
    const int l = t & 63;
    const int blk = blockIdx.x;
    const int row0 = blk * RB;

    const int sr = t >> 2;        // staging row 0..63
    const int kp = t & 3;         // staging col-part 0..3 (16 cols each)
    const float* uRow = user  + (size_t)(row0 + sr) * Hd;
    const float* mRow = music + (size_t)(row0 + sr) * Hd;

    ff4 accL[16], accD[16];
#pragma unroll
    for (int i = 0; i < 16; ++i) { accL[i] = (ff4)0.0f; accD[i] = (ff4)0.0f; }
    float p0 = 0.f, p1 = 0.f, sd2 = 0.f;

    const int la = l & 15, lb = l >> 4;
    const int aoff = (w * 16 + la) * SPAD;
    const int koff8 = lb << 3;

    for (int kc = 0; kc < Hd; kc += KC) {
        __syncthreads();
        // stage memory chunk [256][64] bf16
#pragma unroll
        for (int i = 0; i < 8; ++i) {
            int c = t + (i << 8);
            int n = c >> 3, kg = c & 7;
            u4v v = *(const u4v*)(memB + (size_t)n * Hd + kc + (kg << 3));
            *(u4v*)(sM + n * SPAD + (kg << 3)) = v;
        }
        // stage s = u*m and d = u-m (bf16), accumulate head + ||d||^2 in f32
        {
            const int col0 = kc + (kp << 4);
            unsigned spk[8], dpk[8];
#pragma unroll
            for (int q = 0; q < 4; ++q) {
                const int cb = col0 + (q << 2);
                ff4 uv  = *(const ff4*)(uRow + cb);
                ff4 mv  = *(const ff4*)(mRow + cb);
                ff4 w01 = *(const ff4*)(Wout + cb * 2);
                ff4 w23 = *(const ff4*)(Wout + cb * 2 + 4);
                float s0 = uv[0] * mv[0], s1 = uv[1] * mv[1];
                float s2 = uv[2] * mv[2], s3 = uv[3] * mv[3];
                float d0 = uv[0] - mv[0], d1 = uv[1] - mv[1];
                float d2 = uv[2] - mv[2], d3 = uv[3] - mv[3];
                p0 = fmaf(s0, w01[0], p0); p1 = fmaf(s0, w01[1], p1);
                p0 = fmaf(s1, w01[2], p0); p1 = fmaf(s1, w01[3], p1);
                p0 = fmaf(s2, w23[0], p0); p1 = fmaf(s2, w23[1], p1);
                p0 = fmaf(s3, w23[2], p0); p1 = fmaf(s3, w23[3], p1);
                sd2 = fmaf(d0, d0, sd2); sd2 = fmaf(d1, d1, sd2);
                sd2 = fmaf(d2, d2, sd2); sd2 = fmaf(d3, d3, sd2);
                spk[q * 2]     = bf16r(s0) | (bf16r(s1) << 16);
                spk[q * 2 + 1] = bf16r(s2) | (bf16r(s3) << 16);
                dpk[q * 2]     = bf16r(d0) | (bf16r(d1) << 16);
                dpk[q * 2 + 1] = bf16r(d2) | (bf16r(d3) << 16);
            }
            u4v v0, v1;
            v0[0] = spk[0]; v0[1] = spk[1]; v0[2] = spk[2]; v0[3] = spk[3];
            v1[0] = spk[4]; v1[1] = spk[5]; v1[2] = spk[6]; v1[3] = spk[7];
            *(u4v*)(sS + sr * SPAD + (kp << 4))     = v0;
            *(u4v*)(sS + sr * SPAD + (kp << 4) + 8) = v1;
            v0[0] = dpk[0]; v0[1] = dpk[1]; v0[2] = dpk[2]; v0[3] = dpk[3];
            v1[0] = dpk[4]; v1[1] = dpk[5]; v1[2] = dpk[6]; v1[3] = dpk[7];
            *(u4v*)(sD + sr * SPAD + (kp << 4))     = v0;
            *(u4v*)(sD + sr * SPAD + (kp << 4) + 8) = v1;
        }
        __syncthreads();
        // MFMA: logits (s @ mem^T) and dm (d @ mem^T), shared B fragments
#pragma unroll
        for (int kk = 0; kk < KC; kk += 32) {
            const int ko = kk + koff8;
            s8v aS = *(const s8v*)(sS + aoff + ko);
            s8v aD = *(const s8v*)(sD + aoff + ko);
#pragma unroll
            for (int nt = 0; nt < 16; ++nt) {
                s8v bM = *(const s8v*)(sM + (nt * 16 + la) * SPAD + ko);
                accL[nt] = __builtin_amdgcn_mfma_f32_16x16x32_bf16(aS, bM, accL[nt], 0, 0, 0);
                accD[nt] = __builtin_amdgcn_mfma_f32_16x16x32_bf16(aD, bM, accD[nt], 0, 0, 0);
            }
        }
    }

    // head + ||d||^2: reduce over the 4 staging lanes of each row
    p0 += __shfl_xor(p0, 1);  p0 += __shfl_xor(p0, 2);
    p1 += __shfl_xor(p1, 1);  p1 += __shfl_xor(p1, 2);
    sd2 += __shfl_xor(sd2, 1); sd2 += __shfl_xor(sd2, 2);
    if (kp == 0) {
        const int grow = row0 + sr;
        out[1 + grow * 2 + 0] = p0 + bout[0];
        out[1 + grow * 2 + 1] = p1 + bout[1];
        sAux[sr] = sd2;
    }
    __syncthreads();   // phase-1 LDS reads done (sM reusable), sAux visible

    // ---- softmax over n, per wave rows; C layout: col=la, row=lb*4+j ----
    float mr0, mr1, mr2, mr3;
    {
        ff4 mx = accL[0];
#pragma unroll
        for (int nt = 1; nt < 16; ++nt) {
            mx[0] = fmaxf(mx[0], accL[nt][0]); mx[1] = fmaxf(mx[1], accL[nt][1]);
            mx[2] = fmaxf(mx[2], accL[nt][2]); mx[3] = fmaxf(mx[3], accL[nt][3]);
        }
#pragma unroll
        for (int s = 1; s < 16; s <<= 1) {
            mx[0] = fmaxf(mx[0], __shfl_xor(mx[0], s));
            mx[1] = fmaxf(mx[1], __shfl_xor(mx[1], s));
            mx[2] = fmaxf(mx[2], __shfl_xor(mx[2], s));
            mx[3] = fmaxf(mx[3], __shfl_xor(mx[3], s));
        }
        mr0 = mx[0]; mr1 = mx[1]; mr2 = mx[2]; mr3 = mx[3];
    }
    ff4 sumv = (ff4)0.0f;
#pragma unroll
    for (int nt = 0; nt < 16; ++nt) {
        accL[nt][0] = __expf(accL[nt][0] - mr0);
        accL[nt][1] = __expf(accL[nt][1] - mr1);
        accL[nt][2] = __expf(accL[nt][2] - mr2);
        accL[nt][3] = __expf(accL[nt][3] - mr3);
        sumv[0] += accL[nt][0]; sumv[1] += accL[nt][1];
        sumv[2] += accL[nt][2]; sumv[3] += accL[nt][3];
    }
#pragma unroll
    for (int s = 1; s < 16; s <<= 1) {
        sumv[0] += __shfl_xor(sumv[0], s); sumv[1] += __shfl_xor(sumv[1], s);
        sumv[2] += __shfl_xor(sumv[2], s); sumv[3] += __shfl_xor(sumv[3], s);
    }
    const float i0v = 1.0f / sumv[0], i1v = 1.0f / sumv[1];
    const float i2v = 1.0f / sumv[2], i3v = 1.0f / sumv[3];
    ff4 cross = (ff4)0.0f;
#pragma unroll
    for (int nt = 0; nt < 16; ++nt) {
        accL[nt][0] *= i0v; accL[nt][1] *= i1v; accL[nt][2] *= i2v; accL[nt][3] *= i3v;
        cross[0] = fmaf(accL[nt][0], accD[nt][0], cross[0]);
        cross[1] = fmaf(accL[nt][1], accD[nt][1], cross[1]);
        cross[2] = fmaf(accL[nt][2], accD[nt][2], cross[2]);
        cross[3] = fmaf(accL[nt][3], accD[nt][3], cross[3]);
    }
#pragma unroll
    for (int s = 1; s < 16; s <<= 1) {
        cross[0] += __shfl_xor(cross[0], s); cross[1] += __shfl_xor(cross[1], s);
        cross[2] += __shfl_xor(cross[2], s); cross[3] += __shfl_xor(cross[3], s);
    }

    // ---- stage attn (bf16) to LDS (aliases sM region), per wave ----
    unsigned short* myAttn = sM + w * (16 * APAD);
    {
        const int rb = lb << 2;
#pragma unroll
        for (int nt = 0; nt < 16; ++nt) {
            const int cc = nt * 16 + la;
            myAttn[(rb + 0) * APAD + cc] = (unsigned short)bf16r(accL[nt][0]);
            myAttn[(rb + 1) * APAD + cc] = (unsigned short)bf16r(accL[nt][1]);
            myAttn[(rb + 2) * APAD + cc] = (unsigned short)bf16r(accL[nt][2]);
            myAttn[(rb + 3) * APAD + cc] = (unsigned short)bf16r(accL[nt][3]);
        }
    }
    __syncthreads();

    // ---- gv = attn @ G (G symmetric -> row-major fragments are valid B) ----
    ff4 accG[16];
#pragma unroll
    for (int i = 0; i < 16; ++i) accG[i] = (ff4)0.0f;
#pragma unroll
    for (int ks = 0; ks < 8; ++ks) {
        const int ko = ks * 32 + koff8;
        s8v aA = *(const s8v*)(myAttn + la * APAD + ko);
#pragma unroll
        for (int nt = 0; nt < 16; ++nt) {
            s8v bG = *(const s8v*)(Gbf + (size_t)(nt * 16 + la) * Nn + ko);
            accG[nt] = __builtin_amdgcn_mfma_f32_16x16x32_bf16(aA, bG, accG[nt], 0, 0, 0);
        }
    }
    ff4 quad = (ff4)0.0f;
#pragma unroll
    for (int nt = 0; nt < 16; ++nt) {
        quad[0] = fmaf(accL[nt][0], accG[nt][0], quad[0]);
        quad[1] = fmaf(accL[nt][1], accG[nt][1], quad[1]);
        quad[2] = fmaf(accL[nt][2], accG[nt][2], quad[2]);
        quad[3] = fmaf(accL[nt][3], accG[nt][3], quad[3]);
    }
#pragma unroll
    for (int s = 1; s < 16; s <<= 1) {
        quad[0] += __shfl_xor(quad[0], s); quad[1] += __shfl_xor(quad[1], s);
        quad[2] += __shfl_xor(quad[2], s); quad[3] += __shfl_xor(quad[3], s);
    }

    // ---- score & per-row loss contribution ----
    if (la < 4) {
        const int jj = la;
        const int r = (lb << 2) + jj;
        float cr = (jj == 0) ? cross[0] : (jj == 1) ? cross[1] : (jj == 2) ? cross[2] : cross[3];
        float qd = (jj == 0) ? quad[0]  : (jj == 1) ? quad[1]  : (jj == 2) ? quad[2]  : quad[3];
        float s2 = sAux[w * 16 + r] + 2.0f * cr + qd;
        float sc = sqrtf(fmaxf(s2, 0.0f));
        const int grow = row0 + w * 16 + r;
        float maskv = (float)(2 * label[grow] - 1);
        sScore[w * 16 + r] = maskv * sc;
    }
    __syncthreads();
    if (t < 64) {
        float v = sScore[t];
#pragma unroll
        for (int s = 1; s < 64; s <<= 1) v += __shfl_xor(v, s);
        if (t == 0) partials[blk] = v;
    }
}

// ---- deterministic final reduction of per-block partials -> loss ----
__global__ void finalize_kernel(const float* __restrict__ partials, float* __restrict__ out,
                                int nblk, float invB) {
    const int t = threadIdx.x;
    float v = 0.f;
    for (int i = t; i < nblk; i += 256) v += partials[i];
#pragma unroll
    for (int s = 1; s < 64; s <<= 1) v += __shfl_xor(v, s);
    __shared__ float ws4[4];
    if ((t & 63) == 0) ws4[t >> 6] = v;
    __syncthreads();
    if (t == 0) out[0] = (ws4[0] + ws4[1] + ws4[2] + ws4[3]) * invB;
}

extern "C" void kernel_launch(void* const* d_in, const int* in_sizes, int n_in,
                              void* d_out, int out_size, void* d_ws, size_t ws_size,
                              hipStream_t stream) {
    const float* user  = (const float*)d_in[0];
    const float* music = (const float*)d_in[1];
    const float* mem   = (const float*)d_in[2];
    const float* Wout  = (const float*)d_in[3];
    const float* bout  = (const float*)d_in[4];
    const int*   label = (const int*)d_in[5];
    const int Bn   = in_sizes[0] / Hd;   // 65536
    const int nblk = Bn / RB;            // 1024

    unsigned short* memB = (unsigned short*)d_ws;
    unsigned short* Gbf  = (unsigned short*)((char*)d_ws + (size_t)Nn * Hd * 2);
    float* partials      = (float*)((char*)d_ws + (size_t)Nn * Hd * 2 + (size_t)Nn * Nn * 2);

    conv_mem_kernel<<<(Nn * Hd) / 1024, 256, 0, stream>>>(mem, memB);
    gram_kernel<<<64, 256, 0, stream>>>(mem, Gbf);
    fused_kernel<<<nblk, 256, 0, stream>>>(user, music, Wout, bout, label, memB, Gbf,
                                           (float*)d_out, partials);
    finalize_kernel<<<1, 256, 0, stream>>>(partials, (float*)d_out, nblk, 1.0f / (float)Bn);
}